// Round 6
// baseline (200.067 us; speedup 1.0000x reference)
//
#include <hip/hip_runtime.h>

// CenterLoss: out = mean_i sqrt( sum_d (x[i,d] - weight[targets[i],d])^2 + EPS )
// x: [N=65536, D=512] f32, weight: [C=1000, D=512] f32, targets: [N] i32.
// HBM-bound: 128 MiB x-stream. Roofline ~134 MB / 6.3 TB/s ~= 21 us.
//
// R5 = R4 with clang ext_vector float4 (HIP_vector_type float4 is not
// accepted by __builtin_nontemporal_load):
//  - RPW=8 compile-time, loop fully unrolled (no runtime bound / break)
//  - targets via readlane -> SGPR w-base (no DS op on the address path)
//  - 2 rows per step: 8 float4 loads in flight, 2 independent butterflies
//  - nontemporal x loads (stream-once; keep 2 MB weight resident in L2)

typedef float f32x4 __attribute__((ext_vector_type(4)));

constexpr int D = 512;
constexpr float EPS = 1e-6f;
constexpr int RPW = 8;                 // rows per wave
constexpr int WPB = 4;                 // waves per block (256 threads)

__global__ __launch_bounds__(256) void centerloss_kernel(
    const float* __restrict__ x,
    const float* __restrict__ w,
    const int*   __restrict__ targets,
    float* __restrict__ out,
    int n_rows, float inv_n)
{
    const int lane = threadIdx.x & 63;
    const int wave = threadIdx.x >> 6;
    const int gw = blockIdx.x * WPB + wave;
    const long base = (long)gw * RPW;

    // One-shot target prefetch: lane k (k<8) holds targets[base+k].
    int tml = 0;
    {
        const long r = base + lane;
        if (lane < RPW && r < (long)n_rows) tml = targets[r];
    }

    float wsum = 0.0f;
    const f32x4 fz = {0.f, 0.f, 0.f, 0.f};

    #pragma unroll
    for (int k = 0; k < RPW; k += 2) {
        const long r0 = base + k;
        const long r1 = base + k + 1;
        const bool v0 = r0 < (long)n_rows;       // wave-uniform guards
        const bool v1 = r1 < (long)n_rows;
        // constant-lane readlane -> SGPR target index (scalar w base address)
        const int t0 = __builtin_amdgcn_readlane(tml, k);
        const int t1 = __builtin_amdgcn_readlane(tml, k + 1);

        const f32x4* __restrict__ xr0 = reinterpret_cast<const f32x4*>(x + r0 * D);
        const f32x4* __restrict__ xr1 = reinterpret_cast<const f32x4*>(x + r1 * D);
        const f32x4* __restrict__ wr0 = reinterpret_cast<const f32x4*>(w + (size_t)t0 * D);
        const f32x4* __restrict__ wr1 = reinterpret_cast<const f32x4*>(w + (size_t)t1 * D);

        f32x4 xa0 = fz, xb0 = fz, wa0 = fz, wb0 = fz;
        f32x4 xa1 = fz, xb1 = fz, wa1 = fz, wb1 = fz;
        if (v0) {
            xa0 = __builtin_nontemporal_load(&xr0[lane]);
            xb0 = __builtin_nontemporal_load(&xr0[lane + 64]);
            wa0 = wr0[lane];
            wb0 = wr0[lane + 64];
        }
        if (v1) {
            xa1 = __builtin_nontemporal_load(&xr1[lane]);
            xb1 = __builtin_nontemporal_load(&xr1[lane + 64]);
            wa1 = wr1[lane];
            wb1 = wr1[lane + 64];
        }

        float a0 = 0.f, a1 = 0.f, d;
        d = xa0.x - wa0.x; a0 = fmaf(d, d, a0);
        d = xa0.y - wa0.y; a0 = fmaf(d, d, a0);
        d = xa0.z - wa0.z; a0 = fmaf(d, d, a0);
        d = xa0.w - wa0.w; a0 = fmaf(d, d, a0);
        d = xb0.x - wb0.x; a0 = fmaf(d, d, a0);
        d = xb0.y - wb0.y; a0 = fmaf(d, d, a0);
        d = xb0.z - wb0.z; a0 = fmaf(d, d, a0);
        d = xb0.w - wb0.w; a0 = fmaf(d, d, a0);

        d = xa1.x - wa1.x; a1 = fmaf(d, d, a1);
        d = xa1.y - wa1.y; a1 = fmaf(d, d, a1);
        d = xa1.z - wa1.z; a1 = fmaf(d, d, a1);
        d = xa1.w - wa1.w; a1 = fmaf(d, d, a1);
        d = xb1.x - wb1.x; a1 = fmaf(d, d, a1);
        d = xb1.y - wb1.y; a1 = fmaf(d, d, a1);
        d = xb1.z - wb1.z; a1 = fmaf(d, d, a1);
        d = xb1.w - wb1.w; a1 = fmaf(d, d, a1);

        // Two independent 64-lane butterflies — chains interleave for ILP.
        #pragma unroll
        for (int off = 1; off < 64; off <<= 1) {
            a0 += __shfl_xor(a0, off, 64);
            a1 += __shfl_xor(a1, off, 64);
        }
        if (v0) wsum += sqrtf(a0 + EPS);
        if (v1) wsum += sqrtf(a1 + EPS);
    }

    // wsum identical across lanes post-butterfly; lane 0 publishes.
    __shared__ float smem[WPB];
    if (lane == 0) smem[wave] = wsum;
    __syncthreads();

    if (threadIdx.x == 0) {
        float s = 0.0f;
        #pragma unroll
        for (int i = 0; i < WPB; ++i) s += smem[i];
        atomicAdd(out, s * inv_n);      // pre-scaled: out = mean
    }
}

extern "C" void kernel_launch(void* const* d_in, const int* in_sizes, int n_in,
                              void* d_out, int out_size, void* d_ws, size_t ws_size,
                              hipStream_t stream) {
    const float* x       = (const float*)d_in[0];
    const float* weight  = (const float*)d_in[1];
    const int*   targets = (const int*)d_in[2];
    float* out = (float*)d_out;

    const int n_rows = in_sizes[2];   // 65536

    // d_out is poisoned to 0xAA before every call; zero it for the atomicAdd.
    (void)hipMemsetAsync(d_out, 0, sizeof(float), stream);

    const int rowsPerBlock = WPB * RPW;                 // 32
    const int grid = (n_rows + rowsPerBlock - 1) / rowsPerBlock;  // 2048
    centerloss_kernel<<<grid, 256, 0, stream>>>(x, weight, targets, out,
                                                n_rows, 1.0f / (float)n_rows);
}